// Round 8
// baseline (159.096 us; speedup 1.0000x reference)
//
#include <hip/hip_runtime.h>
#include <math.h>

typedef unsigned short ushort_t;
typedef unsigned int uint_t;
typedef __attribute__((ext_vector_type(8))) short short8;   // 8 bf16 (4 VGPRs)
typedef __attribute__((ext_vector_type(4))) float f32x4;    // MFMA acc

#define B 4096
#define D 512
#define MARGIN 0.3f
#define EPSD 1e-12f
#define NT 16              // K tiles of 32
#define GRID_MINE 1024

__device__ inline ushort_t f2bf_rn(float x) {
    uint_t u = __float_as_uint(x);
    uint_t r = (u + 0x7fffu + ((u >> 16) & 1u)) >> 16;
    return (ushort_t)r;
}
__device__ inline void gload_lds16(const void* g, void* l) {
    __builtin_amdgcn_global_load_lds(
        (const __attribute__((address_space(1))) void*)g,
        (__attribute__((address_space(3))) void*)l, 16, 0, 0);
}

// ---------------------------------------------------------------------------
// Kernel 1: per-row sqnorm (fp32, exact) + fp32 -> bf16 conversion. One wave/row.
// Also re-inits hp/hn bit-arrays and the ticket (every call — re-poison safe).
// ---------------------------------------------------------------------------
__global__ __launch_bounds__(256) void prep_kernel(const float* __restrict__ E,
                                                   float* __restrict__ sq,
                                                   ushort_t* __restrict__ Ehi,
                                                   uint_t* __restrict__ hp_bits,
                                                   uint_t* __restrict__ hn_bits,
                                                   int* __restrict__ ticket) {
    int gid  = blockIdx.x * 256 + threadIdx.x;
    int w    = gid >> 6;          // row
    int lane = gid & 63;
    const float4* row = (const float4*)(E + (size_t)w * D);
    float4 a = row[lane];
    float4 b = row[lane + 64];

    float s = a.x * a.x + a.y * a.y + a.z * a.z + a.w * a.w
            + b.x * b.x + b.y * b.y + b.z * b.z + b.w * b.w;
#pragma unroll
    for (int o = 32; o; o >>= 1) s += __shfl_down(s, o);
    if (lane == 0) sq[w] = s;

    float va[8] = {a.x, a.y, a.z, a.w, b.x, b.y, b.z, b.w};
    ushort_t hi[8];
#pragma unroll
    for (int i = 0; i < 8; ++i) hi[i] = f2bf_rn(va[i]);
    ushort4* ph = (ushort4*)(Ehi + (size_t)w * D);
    ph[lane]      = make_ushort4(hi[0], hi[1], hi[2], hi[3]);
    ph[lane + 64] = make_ushort4(hi[4], hi[5], hi[6], hi[7]);

    if (gid < B) { hp_bits[gid] = 0u; hn_bits[gid] = 0x7f800000u; }  // 0 / +inf
    if (gid == 0) ticket[0] = 0;
}

// ---------------------------------------------------------------------------
// Kernel 2: MFMA distance + batch-hard mining + fused final reduce.
// 128x128 tile/block, 4 waves 2x2. Pure-bf16 dot.
// Minimum-2-phase schedule (T3 recipe, m248v2): double-buffered LDS,
// stage(t+1) issued BEFORE compute(t), ONE __syncthreads per iteration
// (its implicit vmcnt(0) drain lands after compute -> load latency hidden).
// No inline asm / sched_barrier — compiler schedules ds_read<->MFMA (m141 lesson).
// ---------------------------------------------------------------------------
__global__ __launch_bounds__(256) void mine_mfma(const ushort_t* __restrict__ Ehi,
                                                 const int* __restrict__ labels,
                                                 const float* __restrict__ sq,
                                                 uint_t* __restrict__ hp_bits,
                                                 uint_t* __restrict__ hn_bits,
                                                 int* __restrict__ ticket,
                                                 float* __restrict__ out) {
    __shared__ char aB[2][8192];             // 2 x 8 KB A tiles
    __shared__ char bB[2][8192];             // 2 x 8 KB B tiles
    __shared__ float  sqr_s[128], sqc_s[128];
    __shared__ int    labr_s[128], labc_s[128];
    __shared__ float  red_s[8];
    __shared__ int    last_s;

    const int tid = threadIdx.x;
    const int w   = tid >> 6;                // wave 0..3
    const int l   = tid & 63;
    const int rt  = blockIdx.x & 31;
    const int ct  = blockIdx.x >> 5;
    const int r0  = rt * 128;
    const int c0  = ct * 128;
    const int wm  = w >> 1;                  // 0..1 row-half
    const int wn  = w & 1;                   // 0..1 col-half

    if (tid < 128) {
        sqr_s[tid]  = sq[r0 + tid];
        labr_s[tid] = labels[r0 + tid];
    } else {
        int t = tid - 128;
        sqc_s[t]  = sq[c0 + t];
        labc_s[t] = labels[c0 + t];
    }

    f32x4 acc[4][4] = {};

    const int srow  = (l >> 2);              // 0..15 within a 16-row group
    const int pslot = (l & 3);               // phys 16B slot

    // prologue: stage tile 0 into buffer 0
#pragma unroll
    for (int i = 0; i < 2; ++i) {
        int rowL  = w * 32 + i * 16 + srow;
        int chunk = pslot ^ ((rowL >> 1) & 3);
        gload_lds16(Ehi + (size_t)(r0 + rowL) * D + 0 + chunk * 8,
                    aB[0] + (w * 32 + i * 16) * 64);
        gload_lds16(Ehi + (size_t)(c0 + rowL) * D + 0 + chunk * 8,
                    bB[0] + (w * 32 + i * 16) * 64);
    }
    __syncthreads();                         // tile 0 ready (drain + barrier)

    for (int t = 0; t < NT; ++t) {
        const int cur = t & 1;
        // stage tile t+1 into the other buffer (freed by the t-1 end barrier)
        if (t + 1 < NT) {
            const int nb = (t + 1) & 1;
            const int kk = (t + 1) * 32;
#pragma unroll
            for (int i = 0; i < 2; ++i) {
                int rowL  = w * 32 + i * 16 + srow;
                int chunk = pslot ^ ((rowL >> 1) & 3);
                gload_lds16(Ehi + (size_t)(r0 + rowL) * D + kk + chunk * 8,
                            aB[nb] + (w * 32 + i * 16) * 64);
                gload_lds16(Ehi + (size_t)(c0 + rowL) * D + kk + chunk * 8,
                            bB[nb] + (w * 32 + i * 16) * 64);
            }
        }

        // compute tile t (compiler interleaves ds_read / MFMA freely)
        short8 af[4], bf[4];
#pragma unroll
        for (int f = 0; f < 4; ++f) {
            int rrA = wm * 64 + f * 16 + (l & 15);
            int sA  = (l >> 4) ^ ((rrA >> 1) & 3);
            af[f] = *(const short8*)(aB[cur] + rrA * 64 + sA * 16);
            int rrB = wn * 64 + f * 16 + (l & 15);
            int sB  = (l >> 4) ^ ((rrB >> 1) & 3);
            bf[f] = *(const short8*)(bB[cur] + rrB * 64 + sB * 16);
        }
#pragma unroll
        for (int fm = 0; fm < 4; ++fm)
#pragma unroll
            for (int fn = 0; fn < 4; ++fn)
                acc[fm][fn] = __builtin_amdgcn_mfma_f32_16x16x32_bf16(
                    af[fm], bf[fn], acc[fm][fn], 0, 0, 0);

        __syncthreads();   // drain vmcnt (stage t+1 done) + all waves done with tile t
    }

    // epilogue: C/D layout col = lane&15, row = (lane>>4)*4 + reg  [m89]
#pragma unroll
    for (int fm = 0; fm < 4; ++fm) {
        const int rbase = wm * 64 + fm * 16 + ((l >> 4) << 2);
        float hp[4], hn[4], sqr[4];
        int   labr[4];
#pragma unroll
        for (int r = 0; r < 4; ++r) {
            sqr[r]  = sqr_s[rbase + r];
            labr[r] = labr_s[rbase + r];
            hp[r] = -INFINITY;
            hn[r] =  INFINITY;
        }
#pragma unroll
        for (int fn = 0; fn < 4; ++fn) {
            const int cl   = wn * 64 + fn * 16 + (l & 15);
            const float sqc = sqc_s[cl];
            const int  labc = labc_s[cl];
            const int  gcol = c0 + cl;
#pragma unroll
            for (int r = 0; r < 4; ++r) {
                float d2   = sqr[r] + sqc - 2.f * acc[fm][fn][r];
                float dist = sqrtf(fmaxf(d2, EPSD));            // >= 1e-6 > 0
                bool same  = (labr[r] == labc);
                bool diag  = ((r0 + rbase + r) == gcol);
                if (same && !diag) hp[r] = fmaxf(hp[r], dist);
                if (!same)         hn[r] = fminf(hn[r], dist);
            }
        }
#pragma unroll
        for (int r = 0; r < 4; ++r) {
#pragma unroll
            for (int m = 1; m < 16; m <<= 1) {
                hp[r] = fmaxf(hp[r], __shfl_xor(hp[r], m));
                hn[r] = fminf(hn[r], __shfl_xor(hn[r], m));
            }
        }
        if ((l & 15) == 0) {
#pragma unroll
            for (int r = 0; r < 4; ++r) {
                const int row = r0 + rbase + r;
                if (hp[r] >= 0.f)                               // skip -inf sentinel
                    atomicMax(&hp_bits[row], __float_as_uint(hp[r]));
                if (hn[r] < INFINITY)
                    atomicMin(&hn_bits[row], __float_as_uint(hn[r]));
            }
        }
    }

    // fused finalize: last-ticket block computes the masked mean
    __threadfence();
    __syncthreads();
    if (tid == 0) last_s = (atomicAdd(ticket, 1) == GRID_MINE - 1);
    __syncthreads();
    if (last_s) {
        float sum = 0.f, cnt = 0.f;
#pragma unroll
        for (int r = tid; r < B; r += 256) {
            uint_t hpb = atomicOr(&hp_bits[r], 0u);   // coherent read-back
            uint_t hnb = atomicOr(&hn_bits[r], 0u);
            if (hpb != 0u && hnb != 0x7f800000u) {
                sum += fmaxf(__uint_as_float(hpb) - __uint_as_float(hnb) + MARGIN, 0.f);
                cnt += 1.f;
            }
        }
#pragma unroll
        for (int o = 32; o; o >>= 1) {
            sum += __shfl_down(sum, o);
            cnt += __shfl_down(cnt, o);
        }
        int lane = tid & 63, wv = tid >> 6;
        if (lane == 0) { red_s[wv] = sum; red_s[4 + wv] = cnt; }
        __syncthreads();
        if (tid == 0) {
            float S = red_s[0] + red_s[1] + red_s[2] + red_s[3];
            float C = red_s[4] + red_s[5] + red_s[6] + red_s[7];
            out[0] = (C > 0.f) ? S / fmaxf(C, 1.f) : 0.f;
        }
    }
}

// ---------------------------------------------------------------------------
extern "C" void kernel_launch(void* const* d_in, const int* in_sizes, int n_in,
                              void* d_out, int out_size, void* d_ws, size_t ws_size,
                              hipStream_t stream) {
    const float* E      = (const float*)d_in[0];
    const int*   labels = (const int*)d_in[1];
    float* out = (float*)d_out;
    float* ws  = (float*)d_ws;

    float*    sq      = ws;                                  // B floats
    uint_t*   hp_bits = (uint_t*)(ws + B);                   // B
    uint_t*   hn_bits = (uint_t*)(ws + 2 * B);               // B
    int*      ticket  = (int*)(ws + 3 * B);                  // 1
    ushort_t* Ehi     = (ushort_t*)(ws + 3 * B + 16);        // B*D bf16

    prep_kernel<<<B / 4, 256, 0, stream>>>(E, sq, Ehi, hp_bits, hn_bits, ticket);
    mine_mfma<<<GRID_MINE, 256, 0, stream>>>(Ehi, labels, sq, hp_bits, hn_bits, ticket, out);
}

// Round 9
// 133.477 us; speedup vs baseline: 1.1919x; 1.1919x over previous
//
#include <hip/hip_runtime.h>
#include <math.h>

typedef unsigned short ushort_t;
typedef unsigned int uint_t;
typedef __attribute__((ext_vector_type(8))) short short8;   // 8 bf16 (4 VGPRs)
typedef __attribute__((ext_vector_type(4))) float f32x4;    // MFMA acc

#define B 4096
#define D 512
#define MARGIN 0.3f
#define EPSD 1e-12f
#define NSEG 64            // 32 col-tiles x 2 col-half-waves

__device__ inline ushort_t f2bf_rn(float x) {
    uint_t u = __float_as_uint(x);
    uint_t r = (u + 0x7fffu + ((u >> 16) & 1u)) >> 16;
    return (ushort_t)r;
}

// ---------------------------------------------------------------------------
// Kernel 1: per-row sqnorm (fp32, exact) + fp32 -> bf16 conversion. One wave/row.
// Zeroes sum/cnt/ticket every call (re-poison safe).
// ---------------------------------------------------------------------------
__global__ __launch_bounds__(256) void prep_kernel(const float* __restrict__ E,
                                                   float* __restrict__ sq,
                                                   ushort_t* __restrict__ Ehi,
                                                   float* __restrict__ sumcnt,
                                                   int* __restrict__ ticket) {
    int gid  = blockIdx.x * 256 + threadIdx.x;
    int w    = gid >> 6;          // row
    int lane = gid & 63;
    const float4* row = (const float4*)(E + (size_t)w * D);
    float4 a = row[lane];
    float4 b = row[lane + 64];

    float s = a.x * a.x + a.y * a.y + a.z * a.z + a.w * a.w
            + b.x * b.x + b.y * b.y + b.z * b.z + b.w * b.w;
#pragma unroll
    for (int o = 32; o; o >>= 1) s += __shfl_down(s, o);
    if (lane == 0) sq[w] = s;

    float va[8] = {a.x, a.y, a.z, a.w, b.x, b.y, b.z, b.w};
    ushort_t hi[8];
#pragma unroll
    for (int i = 0; i < 8; ++i) hi[i] = f2bf_rn(va[i]);
    ushort4* ph = (ushort4*)(Ehi + (size_t)w * D);
    ph[lane]      = make_ushort4(hi[0], hi[1], hi[2], hi[3]);
    ph[lane + 64] = make_ushort4(hi[4], hi[5], hi[6], hi[7]);

    if (gid == 0) { sumcnt[0] = 0.f; sumcnt[1] = 0.f; ticket[0] = 0; }
}

// ---------------------------------------------------------------------------
// Kernel 2: MFMA distance + batch-hard mining — ZERO LDS tiles, zero barriers.
// 128x128 tile/block, 4 waves 2x2. Fragments loaded directly from global:
// Ehi is 4 MB -> L2-resident; each 64-lane fragment load touches exactly
// 16 full 64B cache lines (lanes l,l+16,l+32,l+48 share a line).
// Per-lane MFMA operand for 16x16x32: row = base + (l&15), k = (l>>4)*8..+8.
// ---------------------------------------------------------------------------
__global__ __launch_bounds__(256) void mine_mfma(const ushort_t* __restrict__ Ehi,
                                                 const int* __restrict__ labels,
                                                 const float* __restrict__ sq,
                                                 float* __restrict__ hp_part,
                                                 float* __restrict__ hn_part) {
    __shared__ float sqr_s[128], sqc_s[128];
    __shared__ int   labr_s[128], labc_s[128];

    const int tid = threadIdx.x;
    const int w   = tid >> 6;                // wave 0..3
    const int l   = tid & 63;
    const int rt  = blockIdx.x & 31;
    const int ct  = blockIdx.x >> 5;
    const int r0  = rt * 128;
    const int c0  = ct * 128;
    const int wm  = w >> 1;                  // 0..1 row-half
    const int wn  = w & 1;                   // 0..1 col-half

    if (tid < 128) {
        sqr_s[tid]  = sq[r0 + tid];
        labr_s[tid] = labels[r0 + tid];
    } else {
        int q = tid - 128;
        sqc_s[q]  = sq[c0 + q];
        labc_s[q] = labels[c0 + q];
    }
    __syncthreads();                         // meta staged (only barrier in kernel)

    // per-lane fragment base pointers
    const ushort_t* aP[4];
    const ushort_t* bP[4];
#pragma unroll
    for (int f = 0; f < 4; ++f) {
        aP[f] = Ehi + (size_t)(r0 + wm * 64 + f * 16 + (l & 15)) * D + (l >> 4) * 8;
        bP[f] = Ehi + (size_t)(c0 + wn * 64 + f * 16 + (l & 15)) * D + (l >> 4) * 8;
    }

    f32x4 acc[4][4] = {};

#pragma unroll 2
    for (int t = 0; t < 16; ++t) {
        const int kk = t * 32;
        short8 af[4], bf[4];
#pragma unroll
        for (int f = 0; f < 4; ++f) af[f] = *(const short8*)(aP[f] + kk);
#pragma unroll
        for (int f = 0; f < 4; ++f) bf[f] = *(const short8*)(bP[f] + kk);
#pragma unroll
        for (int fm = 0; fm < 4; ++fm)
#pragma unroll
            for (int fn = 0; fn < 4; ++fn)
                acc[fm][fn] = __builtin_amdgcn_mfma_f32_16x16x32_bf16(
                    af[fm], bf[fn], acc[fm][fn], 0, 0, 0);
    }

    // epilogue: C/D layout col = lane&15, row = (lane>>4)*4 + reg  [m89]
#pragma unroll
    for (int fm = 0; fm < 4; ++fm) {
        const int rbase = wm * 64 + fm * 16 + ((l >> 4) << 2);
        float hp[4], hn[4], sqr[4];
        int   labr[4];
#pragma unroll
        for (int r = 0; r < 4; ++r) {
            sqr[r]  = sqr_s[rbase + r];
            labr[r] = labr_s[rbase + r];
            hp[r] = -INFINITY;
            hn[r] =  INFINITY;
        }
#pragma unroll
        for (int fn = 0; fn < 4; ++fn) {
            const int cl   = wn * 64 + fn * 16 + (l & 15);
            const float sqc = sqc_s[cl];
            const int  labc = labc_s[cl];
            const int  gcol = c0 + cl;
#pragma unroll
            for (int r = 0; r < 4; ++r) {
                float d2   = sqr[r] + sqc - 2.f * acc[fm][fn][r];
                float dist = sqrtf(fmaxf(d2, EPSD));
                bool same  = (labr[r] == labc);
                bool diag  = ((r0 + rbase + r) == gcol);
                if (same && !diag) hp[r] = fmaxf(hp[r], dist);
                if (!same)         hn[r] = fminf(hn[r], dist);
            }
        }
#pragma unroll
        for (int r = 0; r < 4; ++r) {
#pragma unroll
            for (int m = 1; m < 16; m <<= 1) {
                hp[r] = fmaxf(hp[r], __shfl_xor(hp[r], m));
                hn[r] = fminf(hn[r], __shfl_xor(hn[r], m));
            }
        }
        if ((l & 15) == 0) {
            const int p = ct * 2 + wn;
#pragma unroll
            for (int r = 0; r < 4; ++r) {
                hp_part[(size_t)p * B + r0 + rbase + r] = hp[r];
                hn_part[(size_t)p * B + r0 + rbase + r] = hn[r];
            }
        }
    }
}

// ---------------------------------------------------------------------------
// Kernel 3: combine segments, masked mean, last-ticket block writes out.
// ---------------------------------------------------------------------------
__global__ __launch_bounds__(256) void finalize_kernel(const float* __restrict__ hp_part,
                                                       const float* __restrict__ hn_part,
                                                       float* __restrict__ sumcnt,
                                                       int* __restrict__ ticket,
                                                       float* __restrict__ out) {
    const int r = blockIdx.x * 256 + threadIdx.x;
    float hp = -INFINITY, hn = INFINITY;
#pragma unroll 8
    for (int s = 0; s < NSEG; ++s) {
        hp = fmaxf(hp, hp_part[(size_t)s * B + r]);
        hn = fminf(hn, hn_part[(size_t)s * B + r]);
    }
    bool valid = (hp > -INFINITY) && (hn < INFINITY);
    float loss = valid ? fmaxf(hp - hn + MARGIN, 0.f) : 0.f;
    float cnt  = valid ? 1.f : 0.f;
#pragma unroll
    for (int o = 32; o; o >>= 1) {
        loss += __shfl_down(loss, o);
        cnt  += __shfl_down(cnt, o);
    }
    __shared__ float ls[4], cs[4];
    int lane = threadIdx.x & 63, wv = threadIdx.x >> 6;
    if (lane == 0) { ls[wv] = loss; cs[wv] = cnt; }
    __syncthreads();
    if (threadIdx.x == 0) {
        atomicAdd(&sumcnt[0], ls[0] + ls[1] + ls[2] + ls[3]);
        atomicAdd(&sumcnt[1], cs[0] + cs[1] + cs[2] + cs[3]);
        __threadfence();
        int t = atomicAdd(ticket, 1);
        if (t == (int)gridDim.x - 1) {
            float S = atomicAdd(&sumcnt[0], 0.f);   // coherent read-back
            float C = atomicAdd(&sumcnt[1], 0.f);
            out[0] = (C > 0.f) ? S / fmaxf(C, 1.f) : 0.f;
        }
    }
}

// ---------------------------------------------------------------------------
extern "C" void kernel_launch(void* const* d_in, const int* in_sizes, int n_in,
                              void* d_out, int out_size, void* d_ws, size_t ws_size,
                              hipStream_t stream) {
    const float* E      = (const float*)d_in[0];
    const int*   labels = (const int*)d_in[1];
    float* out = (float*)d_out;
    float* ws  = (float*)d_ws;

    float*    sq      = ws;                                  // B floats
    float*    hp_part = ws + B;                              // NSEG*B
    float*    hn_part = ws + B + NSEG * B;                   // NSEG*B
    float*    sumcnt  = ws + B + 2 * NSEG * B;               // 2
    int*      ticket  = (int*)(ws + B + 2 * NSEG * B + 8);   // 1
    ushort_t* Ehi     = (ushort_t*)(ws + B + 2 * NSEG * B + 16);

    prep_kernel<<<B / 4, 256, 0, stream>>>(E, sq, Ehi, sumcnt, ticket);
    mine_mfma<<<32 * 32, 256, 0, stream>>>(Ehi, labels, sq, hp_part, hn_part);
    finalize_kernel<<<B / 256, 256, 0, stream>>>(hp_part, hn_part, sumcnt, ticket, out);
}

// Round 10
// 103.980 us; speedup vs baseline: 1.5301x; 1.2837x over previous
//
#include <hip/hip_runtime.h>
#include <math.h>

typedef unsigned short ushort_t;
typedef unsigned int uint_t;
typedef __attribute__((ext_vector_type(8))) short short8;   // 8 bf16 (4 VGPRs)
typedef __attribute__((ext_vector_type(4))) float f32x4;    // MFMA acc

#define B 4096
#define D 512
#define MARGIN 0.3f
#define EPSD 1e-12f
#define NSEG 64            // 32 col-tiles x 2 col-half-waves
#define NT 8               // K tiles of 64

__device__ inline ushort_t f2bf_rn(float x) {
    uint_t u = __float_as_uint(x);
    uint_t r = (u + 0x7fffu + ((u >> 16) & 1u)) >> 16;
    return (ushort_t)r;
}
__device__ inline void gload_lds16(const void* g, void* l) {
    __builtin_amdgcn_global_load_lds(
        (const __attribute__((address_space(1))) void*)g,
        (__attribute__((address_space(3))) void*)l, 16, 0, 0);
}

// ---------------------------------------------------------------------------
// Kernel 1: per-row sqnorm (fp32, exact) + fp32 -> bf16 conversion. One wave/row.
// Zeroes sum/cnt/ticket every call (re-poison safe).
// ---------------------------------------------------------------------------
__global__ __launch_bounds__(256) void prep_kernel(const float* __restrict__ E,
                                                   float* __restrict__ sq,
                                                   ushort_t* __restrict__ Ehi,
                                                   float* __restrict__ sumcnt,
                                                   int* __restrict__ ticket) {
    int gid  = blockIdx.x * 256 + threadIdx.x;
    int w    = gid >> 6;          // row
    int lane = gid & 63;
    const float4* row = (const float4*)(E + (size_t)w * D);
    float4 a = row[lane];
    float4 b = row[lane + 64];

    float s = a.x * a.x + a.y * a.y + a.z * a.z + a.w * a.w
            + b.x * b.x + b.y * b.y + b.z * b.z + b.w * b.w;
#pragma unroll
    for (int o = 32; o; o >>= 1) s += __shfl_down(s, o);
    if (lane == 0) sq[w] = s;

    float va[8] = {a.x, a.y, a.z, a.w, b.x, b.y, b.z, b.w};
    ushort_t hi[8];
#pragma unroll
    for (int i = 0; i < 8; ++i) hi[i] = f2bf_rn(va[i]);
    ushort4* ph = (ushort4*)(Ehi + (size_t)w * D);
    ph[lane]      = make_ushort4(hi[0], hi[1], hi[2], hi[3]);
    ph[lane + 64] = make_ushort4(hi[4], hi[5], hi[6], hi[7]);

    if (gid == 0) { sumcnt[0] = 0.f; sumcnt[1] = 0.f; ticket[0] = 0; }
}

// ---------------------------------------------------------------------------
// Kernel 2: MFMA distance + batch-hard mining. 128x128 tile/block, 4 waves 2x2.
// R6 structure (single-buffer LDS, stage -> sync -> compute -> sync), but
// BK=64: 8 K-tiles instead of 16 -> half the sync+drain pairs.
// LDS row = 128 B (64 bf16), 8 chunks of 16 B. Swizzle: phys_chunk =
// logical_chunk ^ (row & 7), applied on the pre-swizzled GLOBAL source
// (linear global_load_lds dest) and on the LDS read (both-sides, rule #21).
// Read conflict check: 16 lanes share a logical chunk across 16 consecutive
// rows -> phys chunks span all 8 bank-groups, 2 lanes each -> 2-way = free.
// ---------------------------------------------------------------------------
__global__ __launch_bounds__(256) void mine_mfma(const ushort_t* __restrict__ Ehi,
                                                 const int* __restrict__ labels,
                                                 const float* __restrict__ sq,
                                                 float* __restrict__ hp_part,
                                                 float* __restrict__ hn_part) {
    __shared__ char aB[16384];               // 128 rows x 128 B
    __shared__ char bB[16384];
    __shared__ float sqr_s[128], sqc_s[128];
    __shared__ int   labr_s[128], labc_s[128];

    const int tid = threadIdx.x;
    const int w   = tid >> 6;                // wave 0..3
    const int l   = tid & 63;
    const int rt  = blockIdx.x & 31;
    const int ct  = blockIdx.x >> 5;
    const int r0  = rt * 128;
    const int c0  = ct * 128;
    const int wm  = w >> 1;                  // 0..1 row-half
    const int wn  = w & 1;                   // 0..1 col-half

    if (tid < 128) {
        sqr_s[tid]  = sq[r0 + tid];
        labr_s[tid] = labels[r0 + tid];
    } else {
        int q = tid - 128;
        sqc_s[q]  = sq[c0 + q];
        labc_s[q] = labels[c0 + q];
    }

    f32x4 acc[4][4] = {};

    const int srow  = (l >> 3);              // 0..7 row within an 8-row group
    const int pslot = (l & 7);               // phys 16B chunk within the row

    for (int t = 0; t < NT; ++t) {
        const int kk0 = t * 64;
        if (t) __syncthreads();              // prev compute done reading LDS
        // stage: per wave 32 rows of A and B, 4 gloads each (8 rows/load)
#pragma unroll
        for (int i = 0; i < 4; ++i) {
            const int rowbase = w * 32 + i * 8;
            const int rowL    = rowbase + srow;
            const int chunk   = pslot ^ (rowL & 7);          // logical chunk
            gload_lds16(Ehi + (size_t)(r0 + rowL) * D + kk0 + chunk * 8,
                        aB + rowbase * 128);
            gload_lds16(Ehi + (size_t)(c0 + rowL) * D + kk0 + chunk * 8,
                        bB + rowbase * 128);
        }
        __syncthreads();                     // drain + all waves' loads done

#pragma unroll
        for (int sub = 0; sub < 2; ++sub) {  // two K=32 sub-tiles
            short8 af[4], bf[4];
#pragma unroll
            for (int f = 0; f < 4; ++f) {
                const int rrA = wm * 64 + f * 16 + (l & 15);
                const int pA  = (4 * sub + (l >> 4)) ^ (rrA & 7);
                af[f] = *(const short8*)(aB + rrA * 128 + pA * 16);
                const int rrB = wn * 64 + f * 16 + (l & 15);
                const int pB  = (4 * sub + (l >> 4)) ^ (rrB & 7);
                bf[f] = *(const short8*)(bB + rrB * 128 + pB * 16);
            }
#pragma unroll
            for (int fm = 0; fm < 4; ++fm)
#pragma unroll
                for (int fn = 0; fn < 4; ++fn)
                    acc[fm][fn] = __builtin_amdgcn_mfma_f32_16x16x32_bf16(
                        af[fm], bf[fn], acc[fm][fn], 0, 0, 0);
        }
    }

    // epilogue: C/D layout col = lane&15, row = (lane>>4)*4 + reg  [m89]
#pragma unroll
    for (int fm = 0; fm < 4; ++fm) {
        const int rbase = wm * 64 + fm * 16 + ((l >> 4) << 2);
        float hp[4], hn[4], sqr[4];
        int   labr[4];
#pragma unroll
        for (int r = 0; r < 4; ++r) {
            sqr[r]  = sqr_s[rbase + r];
            labr[r] = labr_s[rbase + r];
            hp[r] = -INFINITY;
            hn[r] =  INFINITY;
        }
#pragma unroll
        for (int fn = 0; fn < 4; ++fn) {
            const int cl   = wn * 64 + fn * 16 + (l & 15);
            const float sqc = sqc_s[cl];
            const int  labc = labc_s[cl];
            const int  gcol = c0 + cl;
#pragma unroll
            for (int r = 0; r < 4; ++r) {
                float d2   = sqr[r] + sqc - 2.f * acc[fm][fn][r];
                float dist = sqrtf(fmaxf(d2, EPSD));
                bool same  = (labr[r] == labc);
                bool diag  = ((r0 + rbase + r) == gcol);
                if (same && !diag) hp[r] = fmaxf(hp[r], dist);
                if (!same)         hn[r] = fminf(hn[r], dist);
            }
        }
#pragma unroll
        for (int r = 0; r < 4; ++r) {
#pragma unroll
            for (int m = 1; m < 16; m <<= 1) {
                hp[r] = fmaxf(hp[r], __shfl_xor(hp[r], m));
                hn[r] = fminf(hn[r], __shfl_xor(hn[r], m));
            }
        }
        if ((l & 15) == 0) {
            const int p = ct * 2 + wn;
#pragma unroll
            for (int r = 0; r < 4; ++r) {
                hp_part[(size_t)p * B + r0 + rbase + r] = hp[r];
                hn_part[(size_t)p * B + r0 + rbase + r] = hn[r];
            }
        }
    }
}

// ---------------------------------------------------------------------------
// Kernel 3: combine segments, masked mean, last-ticket block writes out.
// ---------------------------------------------------------------------------
__global__ __launch_bounds__(256) void finalize_kernel(const float* __restrict__ hp_part,
                                                       const float* __restrict__ hn_part,
                                                       float* __restrict__ sumcnt,
                                                       int* __restrict__ ticket,
                                                       float* __restrict__ out) {
    const int r = blockIdx.x * 256 + threadIdx.x;
    float hp = -INFINITY, hn = INFINITY;
#pragma unroll 8
    for (int s = 0; s < NSEG; ++s) {
        hp = fmaxf(hp, hp_part[(size_t)s * B + r]);
        hn = fminf(hn, hn_part[(size_t)s * B + r]);
    }
    bool valid = (hp > -INFINITY) && (hn < INFINITY);
    float loss = valid ? fmaxf(hp - hn + MARGIN, 0.f) : 0.f;
    float cnt  = valid ? 1.f : 0.f;
#pragma unroll
    for (int o = 32; o; o >>= 1) {
        loss += __shfl_down(loss, o);
        cnt  += __shfl_down(cnt, o);
    }
    __shared__ float ls[4], cs[4];
    int lane = threadIdx.x & 63, wv = threadIdx.x >> 6;
    if (lane == 0) { ls[wv] = loss; cs[wv] = cnt; }
    __syncthreads();
    if (threadIdx.x == 0) {
        atomicAdd(&sumcnt[0], ls[0] + ls[1] + ls[2] + ls[3]);
        atomicAdd(&sumcnt[1], cs[0] + cs[1] + cs[2] + cs[3]);
        __threadfence();
        int t = atomicAdd(ticket, 1);
        if (t == (int)gridDim.x - 1) {
            float S = atomicAdd(&sumcnt[0], 0.f);   // coherent read-back
            float C = atomicAdd(&sumcnt[1], 0.f);
            out[0] = (C > 0.f) ? S / fmaxf(C, 1.f) : 0.f;
        }
    }
}

// ---------------------------------------------------------------------------
extern "C" void kernel_launch(void* const* d_in, const int* in_sizes, int n_in,
                              void* d_out, int out_size, void* d_ws, size_t ws_size,
                              hipStream_t stream) {
    const float* E      = (const float*)d_in[0];
    const int*   labels = (const int*)d_in[1];
    float* out = (float*)d_out;
    float* ws  = (float*)d_ws;

    float*    sq      = ws;                                  // B floats
    float*    hp_part = ws + B;                              // NSEG*B
    float*    hn_part = ws + B + NSEG * B;                   // NSEG*B
    float*    sumcnt  = ws + B + 2 * NSEG * B;               // 2
    int*      ticket  = (int*)(ws + B + 2 * NSEG * B + 8);   // 1
    ushort_t* Ehi     = (ushort_t*)(ws + B + 2 * NSEG * B + 16);

    prep_kernel<<<B / 4, 256, 0, stream>>>(E, sq, Ehi, sumcnt, ticket);
    mine_mfma<<<32 * 32, 256, 0, stream>>>(Ehi, labels, sq, hp_part, hn_part);
    finalize_kernel<<<B / 256, 256, 0, stream>>>(hp_part, hn_part, sumcnt, ticket, out);
}